// Round 3
// baseline (482.402 us; speedup 1.0000x reference)
//
#include <hip/hip_runtime.h>

typedef __attribute__((ext_vector_type(8))) short short8;   // 8 bf16
typedef __attribute__((ext_vector_type(4))) float f32x4;

#define QLEN     32
#define DIM      128
#define D_COUNT  2048
#define DLEN     180
#define DOCS     4
#define NBLK     (D_COUNT / DOCS)     // 512 blocks = 2 per CU
#define CROWS    90                   // rows per chunk (2 chunks/doc)
#define CF4      2880                 // float4s per chunk (90*32)
#define NTC      6                    // 16-row tiles per chunk (last masked to 10 rows)

// f32 -> bf16 round-to-nearest-even
static __device__ __forceinline__ unsigned short f2bf(float x) {
    union { float f; unsigned int u; } v; v.f = x;
    unsigned int r = v.u + 0x7fffu + ((v.u >> 16) & 1u);
    return (unsigned short)(r >> 16);
}

static __device__ __forceinline__ unsigned long long pack4(float4 v) {
    return (unsigned long long)f2bf(v.x)
         | ((unsigned long long)f2bf(v.y) << 16)
         | ((unsigned long long)f2bf(v.z) << 32)
         | ((unsigned long long)f2bf(v.w) << 48);
}

__global__ __launch_bounds__(512, 4) void maxsim_kernel(
    const float* __restrict__ Q, const float* __restrict__ D,
    float* __restrict__ out)
{
    // 2 chunk buffers, bf16, row stride 256 B, XOR swizzle (row&7)<<4.
    // 2 x 22.5 KiB = 45 KiB total -> 2 blocks/CU (LDS) with VGPR<=128 (4 w/SIMD).
    __shared__ __align__(16) unsigned char smem[2][CROWS * 256];

    const int tid  = threadIdx.x;
    const int wave = tid >> 6;
    const int lane = tid & 63;
    const int lr   = lane & 15;   // A row within tile / B-C s column
    const int lg   = lane >> 4;   // k-group

    // ---- A fragments for this wave's 2 queries, held in regs all kernel ----
    short8 afr[2][2][4];   // [query][mtile][kstep]
    #pragma unroll
    for (int qi = 0; qi < 2; ++qi) {
        const int q = wave * 2 + qi;
        #pragma unroll
        for (int mt = 0; mt < 2; ++mt) {
            #pragma unroll
            for (int ks = 0; ks < 4; ++ks) {
                const float* p = Q + (size_t)(q * QLEN + mt * 16 + lr) * DIM
                                   + ks * 32 + lg * 8;
                float4 a = *(const float4*)p;
                float4 b = *(const float4*)(p + 4);
                short8 fr;
                fr[0] = (short)f2bf(a.x); fr[1] = (short)f2bf(a.y);
                fr[2] = (short)f2bf(a.z); fr[3] = (short)f2bf(a.w);
                fr[4] = (short)f2bf(b.x); fr[5] = (short)f2bf(b.y);
                fr[6] = (short)f2bf(b.z); fr[7] = (short)f2bf(b.w);
                afr[qi][mt][ks] = fr;
            }
        }
    }

    const int k0 = blockIdx.x * DOCS;
    float4 r[6];    // staging regs for one 90-row chunk: 5*512 + 320 float4

    // issue chunk c's global loads (stay in flight until cwrite)
    auto issue = [&](int c) {
        const float4* Dk = (const float4*)(D + (size_t)(k0 + (c >> 1)) * (DLEN * DIM))
                         + (c & 1) * CF4;
        #pragma unroll
        for (int i = 0; i < 5; ++i) r[i] = Dk[i * 512 + tid];
        if (tid < CF4 - 5 * 512) r[5] = Dk[5 * 512 + tid];
    };
    // convert + swizzled LDS write (compiler inserts the vmcnt waits on r[])
    auto cwrite = [&](unsigned char* s) {
        #pragma unroll
        for (int i = 0; i < 5; ++i) {
            int f = i * 512 + tid;
            int row = f >> 5, g = f & 31;
            unsigned off = ((unsigned)(row * 256 + g * 8)) ^ (((unsigned)row & 7u) << 4);
            *(unsigned long long*)(s + off) = pack4(r[i]);
        }
        if (tid < CF4 - 5 * 512) {
            int f = 5 * 512 + tid;
            int row = f >> 5, g = f & 31;
            unsigned off = ((unsigned)(row * 256 + g * 8)) ^ (((unsigned)row & 7u) << 4);
            *(unsigned long long*)(s + off) = pack4(r[5]);
        }
    };

    f32x4 rm[2][2];
    auto compute_chunk = [&](const unsigned char* s) {
        #pragma unroll
        for (int nt = 0; nt < NTC; ++nt) {
            const int srow = nt * 16 + lr;
            const int rrow = (srow < CROWS) ? srow : srow - 16;  // tail reads valid rows
            const unsigned rowbase = (unsigned)rrow * 256u;
            const unsigned sx = (((unsigned)rrow) & 7u) << 4;
            f32x4 acc[2][2];
            #pragma unroll
            for (int a = 0; a < 2; ++a)
                #pragma unroll
                for (int b = 0; b < 2; ++b)
                    acc[a][b] = f32x4{0.f, 0.f, 0.f, 0.f};
            __builtin_amdgcn_s_setprio(1);
            #pragma unroll
            for (int ks = 0; ks < 4; ++ks) {
                // one B fragment feeds 4 MFMAs (2 queries x 2 m-tiles)
                short8 bf = *(const short8*)(s + rowbase
                             + (((unsigned)(ks * 64 + lg * 16)) ^ sx));
                acc[0][0] = __builtin_amdgcn_mfma_f32_16x16x32_bf16(afr[0][0][ks], bf, acc[0][0], 0, 0, 0);
                acc[0][1] = __builtin_amdgcn_mfma_f32_16x16x32_bf16(afr[0][1][ks], bf, acc[0][1], 0, 0, 0);
                acc[1][0] = __builtin_amdgcn_mfma_f32_16x16x32_bf16(afr[1][0][ks], bf, acc[1][0], 0, 0, 0);
                acc[1][1] = __builtin_amdgcn_mfma_f32_16x16x32_bf16(afr[1][1][ks], bf, acc[1][1], 0, 0, 0);
            }
            __builtin_amdgcn_s_setprio(0);
            const bool valid = (nt < NTC - 1) || (lr < CROWS - (NTC - 1) * 16); // lr<10
            #pragma unroll
            for (int a = 0; a < 2; ++a)
                #pragma unroll
                for (int b = 0; b < 2; ++b)
                    #pragma unroll
                    for (int i = 0; i < 4; ++i)
                        rm[a][b][i] = fmaxf(rm[a][b][i], valid ? acc[a][b][i] : -INFINITY);
        }
    };

    auto sync = [&]() {
        asm volatile("s_waitcnt lgkmcnt(0)" ::: "memory");
        __builtin_amdgcn_s_barrier();     // raw barrier: global loads stay in flight
        asm volatile("" ::: "memory");
    };

    // ---- prologue: chunk0 -> buf0; chunk1 loads in flight ----
    issue(0);
    cwrite(smem[0]);
    issue(1);
    sync();

    #pragma unroll 1
    for (int d = 0; d < DOCS; ++d) {
        #pragma unroll
        for (int a = 0; a < 2; ++a)
            #pragma unroll
            for (int b = 0; b < 2; ++b)
                rm[a][b] = f32x4{-INFINITY, -INFINITY, -INFINITY, -INFINITY};

        // even chunk (2d) from buf0; stage chunk 2d+1 -> buf1
        compute_chunk(smem[0]);
        cwrite(smem[1]);
        if (d < DOCS - 1) issue(2 * d + 2);
        sync();

        // odd chunk (2d+1) from buf1; stage chunk 2d+2 -> buf0
        compute_chunk(smem[1]);

        // ---- reduce: max over s (lane bits 0..3), then sum over m ----
        #pragma unroll
        for (int m = 1; m <= 8; m <<= 1)
            #pragma unroll
            for (int a = 0; a < 2; ++a)
                #pragma unroll
                for (int b = 0; b < 2; ++b)
                    #pragma unroll
                    for (int i = 0; i < 4; ++i)
                        rm[a][b][i] = fmaxf(rm[a][b][i], __shfl_xor(rm[a][b][i], m, 64));
        #pragma unroll
        for (int qi = 0; qi < 2; ++qi) {
            float part = (rm[qi][0][0] + rm[qi][0][1]) + (rm[qi][0][2] + rm[qi][0][3])
                       + (rm[qi][1][0] + rm[qi][1][1]) + (rm[qi][1][2] + rm[qi][1][3]);
            part += __shfl_xor(part, 16, 64);
            part += __shfl_xor(part, 32, 64);
            if (lane == 0)
                out[(size_t)(wave * 2 + qi) * D_COUNT + (k0 + d)] = part;
        }

        if (d < DOCS - 1) {
            cwrite(smem[0]);
            issue(2 * d + 3);
            sync();
        }
    }
}

extern "C" void kernel_launch(void* const* d_in, const int* in_sizes, int n_in,
                              void* d_out, int out_size, void* d_ws, size_t ws_size,
                              hipStream_t stream) {
    const float* Q = (const float*)d_in[0];
    const float* D = (const float*)d_in[1];
    float* out = (float*)d_out;
    maxsim_kernel<<<dim3(NBLK), dim3(512), 0, stream>>>(Q, D, out);
}

// Round 4
// 272.287 us; speedup vs baseline: 1.7717x; 1.7717x over previous
//
#include <hip/hip_runtime.h>

typedef __attribute__((ext_vector_type(8))) short short8;   // 8 bf16
typedef __attribute__((ext_vector_type(4))) float f32x4;

#define QLEN     32
#define DIM      128
#define D_COUNT  2048
#define DLEN     180
#define DOCS     4
#define NBLK     (D_COUNT / DOCS)     // 512 blocks -> 2 per CU
#define CROWS    90                   // rows per chunk (2 chunks/doc)
#define CF4      2880                 // float4s per chunk (90*32)
#define NTC      6                    // 16-row s-tiles per chunk (last masked to 10 rows)

// f32 -> bf16 round-to-nearest-even
static __device__ __forceinline__ unsigned short f2bf(float x) {
    union { float f; unsigned int u; } v; v.f = x;
    unsigned int r = v.u + 0x7fffu + ((v.u >> 16) & 1u);
    return (unsigned short)(r >> 16);
}

static __device__ __forceinline__ unsigned long long pack4(float4 v) {
    return (unsigned long long)f2bf(v.x)
         | ((unsigned long long)f2bf(v.y) << 16)
         | ((unsigned long long)f2bf(v.z) << 32)
         | ((unsigned long long)f2bf(v.w) << 48);
}

// swizzled LDS byte offset for float4-slot f (row = f>>5, 8B granule g = f&31)
static __device__ __forceinline__ unsigned lds_off(int f) {
    int row = f >> 5, g = f & 31;
    return ((unsigned)(row * 256 + g * 8)) ^ (((unsigned)row & 7u) << 4);
}

__global__ __launch_bounds__(512, 2) void maxsim_kernel(
    const float* __restrict__ Q, const float* __restrict__ D,
    float* __restrict__ out)
{
    // 2 chunk buffers, bf16, row stride 256 B, XOR swizzle (row&7)<<4.
    // 2 x 22.5 KiB = 45 KiB -> 2 blocks/CU if VGPR <= 128 (why launch_bounds(512,2):
    // (512,4) makes the allocator split arch/acc 64/64 and spill — R3 showed 1 GB scratch).
    __shared__ __align__(16) unsigned char smem[2][CROWS * 256];

    const int tid  = threadIdx.x;
    const int wave = tid >> 6;
    const int lane = tid & 63;
    const int lr   = lane & 15;
    const int lg   = lane >> 4;

    // ---- Q fragments for this wave's 2 queries (resident all kernel).
    // Per-lane elements serve as MFMA *B* operand: col=lane&15 -> m-row, k=lg*8+j.
    short8 afr[2][2][4];   // [query][mtile][kstep]
    #pragma unroll
    for (int qi = 0; qi < 2; ++qi) {
        const int q = wave * 2 + qi;
        #pragma unroll
        for (int mt = 0; mt < 2; ++mt) {
            #pragma unroll
            for (int ks = 0; ks < 4; ++ks) {
                const float* p = Q + (size_t)(q * QLEN + mt * 16 + lr) * DIM
                                   + ks * 32 + lg * 8;
                float4 a = *(const float4*)p;
                float4 b = *(const float4*)(p + 4);
                short8 fr;
                fr[0] = (short)f2bf(a.x); fr[1] = (short)f2bf(a.y);
                fr[2] = (short)f2bf(a.z); fr[3] = (short)f2bf(a.w);
                fr[4] = (short)f2bf(b.x); fr[5] = (short)f2bf(b.y);
                fr[6] = (short)f2bf(b.z); fr[7] = (short)f2bf(b.w);
                afr[qi][mt][ks] = fr;
            }
        }
    }

    const int k0 = blockIdx.x * DOCS;

    // staging regs: P0 = 4 float4 (issued a phase early), P1 = 2 float4 (issued late)
    float4 r0, r1, r2, r3, r4, r5;

    auto chunk_base = [&](int c) {
        return (const float4*)(D + (size_t)(k0 + (c >> 1)) * (DLEN * DIM)) + (c & 1) * CF4;
    };
    auto issueP0 = [&](int c) {
        const float4* p = chunk_base(c);
        r0 = p[tid]; r1 = p[512 + tid]; r2 = p[1024 + tid]; r3 = p[1536 + tid];
    };
    auto issueP1 = [&](int c) {
        const float4* p = chunk_base(c);
        r4 = p[2048 + tid];
        if (tid < CF4 - 2560) r5 = p[2560 + tid];   // tid < 320
    };
    auto cwriteP0 = [&](unsigned char* s) {
        *(unsigned long long*)(s + lds_off(tid))        = pack4(r0);
        *(unsigned long long*)(s + lds_off(512 + tid))  = pack4(r1);
        *(unsigned long long*)(s + lds_off(1024 + tid)) = pack4(r2);
        *(unsigned long long*)(s + lds_off(1536 + tid)) = pack4(r3);
    };
    auto cwriteP1 = [&](unsigned char* s) {
        *(unsigned long long*)(s + lds_off(2048 + tid)) = pack4(r4);
        if (tid < CF4 - 2560)
            *(unsigned long long*)(s + lds_off(2560 + tid)) = pack4(r5);
    };

    // rm[qi][mt][i]: running max over s; C layout (swapped): col=lane&15 -> q·m,
    // row = lg*4 + i -> s within tile
    f32x4 rm[2][2];

    auto compute_chunk = [&](const unsigned char* s) {
        #pragma unroll
        for (int nt = 0; nt < NTC; ++nt) {
            const int srow = nt * 16 + lr;
            const int rrow = (srow < CROWS) ? srow : srow - 16;  // tail tile reads valid rows
            const unsigned rowbase = (unsigned)rrow * 256u;
            const unsigned sx = (((unsigned)rrow) & 7u) << 4;
            f32x4 acc[2][2];
            #pragma unroll
            for (int a = 0; a < 2; ++a)
                #pragma unroll
                for (int b = 0; b < 2; ++b)
                    acc[a][b] = f32x4{0.f, 0.f, 0.f, 0.f};
            __builtin_amdgcn_s_setprio(1);
            #pragma unroll
            for (int ks = 0; ks < 4; ++ks) {
                // D fragment as MFMA *A* operand: row=lane&15 -> s, k=lg*8+j
                short8 df = *(const short8*)(s + rowbase
                             + (((unsigned)(ks * 64 + lg * 16)) ^ sx));
                acc[0][0] = __builtin_amdgcn_mfma_f32_16x16x32_bf16(df, afr[0][0][ks], acc[0][0], 0, 0, 0);
                acc[0][1] = __builtin_amdgcn_mfma_f32_16x16x32_bf16(df, afr[0][1][ks], acc[0][1], 0, 0, 0);
                acc[1][0] = __builtin_amdgcn_mfma_f32_16x16x32_bf16(df, afr[1][0][ks], acc[1][0], 0, 0, 0);
                acc[1][1] = __builtin_amdgcn_mfma_f32_16x16x32_bf16(df, afr[1][1][ks], acc[1][1], 0, 0, 0);
            }
            __builtin_amdgcn_s_setprio(0);
            if (nt < NTC - 1) {
                #pragma unroll
                for (int a = 0; a < 2; ++a)
                    #pragma unroll
                    for (int b = 0; b < 2; ++b)
                        #pragma unroll
                        for (int i = 0; i < 4; ++i)
                            rm[a][b][i] = fmaxf(rm[a][b][i], acc[a][b][i]);
            } else {
                // C-rows s = 80 + lg*4 + i; valid iff lg*4 + i < 10
                #pragma unroll
                for (int i = 0; i < 4; ++i) {
                    const bool valid = (lg * 4 + i) < (CROWS - (NTC - 1) * 16);
                    #pragma unroll
                    for (int a = 0; a < 2; ++a)
                        #pragma unroll
                        for (int b = 0; b < 2; ++b)
                            rm[a][b][i] = fmaxf(rm[a][b][i], valid ? acc[a][b][i] : -INFINITY);
                }
            }
        }
    };

    auto sync = [&]() {
        asm volatile("s_waitcnt lgkmcnt(0)" ::: "memory");
        __builtin_amdgcn_s_barrier();     // raw barrier: global loads stay in flight
        asm volatile("" ::: "memory");
    };

    // ---- prologue: chunk0 -> buf0; chunk1 P0 in flight ----
    issueP0(0); issueP1(0);
    cwriteP0(smem[0]); cwriteP1(smem[0]);
    issueP0(1);
    sync();

    #pragma unroll 1
    for (int d = 0; d < DOCS; ++d) {
        #pragma unroll
        for (int a = 0; a < 2; ++a)
            #pragma unroll
            for (int b = 0; b < 2; ++b)
                rm[a][b] = f32x4{-INFINITY, -INFINITY, -INFINITY, -INFINITY};

        // even chunk (2d) from buf0; finish staging chunk 2d+1 -> buf1
        compute_chunk(smem[0]);
        cwriteP0(smem[1]);                 // waits vmcnt on P0(2d+1)
        issueP1(2 * d + 1);
        cwriteP1(smem[1]);
        if (d < DOCS - 1) issueP0(2 * d + 2);
        sync();

        // odd chunk (2d+1) from buf1
        compute_chunk(smem[1]);

        // ---- reduce: in-lane max over i, xor16/32 max over s-groups,
        //      then sum over m (in-lane pair add + xor1..8) ----
        float v00 = fmaxf(fmaxf(rm[0][0][0], rm[0][0][1]), fmaxf(rm[0][0][2], rm[0][0][3]));
        float v01 = fmaxf(fmaxf(rm[0][1][0], rm[0][1][1]), fmaxf(rm[0][1][2], rm[0][1][3]));
        float v10 = fmaxf(fmaxf(rm[1][0][0], rm[1][0][1]), fmaxf(rm[1][0][2], rm[1][0][3]));
        float v11 = fmaxf(fmaxf(rm[1][1][0], rm[1][1][1]), fmaxf(rm[1][1][2], rm[1][1][3]));
        #pragma unroll
        for (int m = 16; m <= 32; m <<= 1) {
            v00 = fmaxf(v00, __shfl_xor(v00, m, 64));
            v01 = fmaxf(v01, __shfl_xor(v01, m, 64));
            v10 = fmaxf(v10, __shfl_xor(v10, m, 64));
            v11 = fmaxf(v11, __shfl_xor(v11, m, 64));
        }
        float t0 = v00 + v01;
        float t1 = v10 + v11;
        #pragma unroll
        for (int m = 1; m <= 8; m <<= 1) {
            t0 += __shfl_xor(t0, m, 64);
            t1 += __shfl_xor(t1, m, 64);
        }
        if (lane == 0) {
            out[(size_t)(wave * 2 + 0) * D_COUNT + (k0 + d)] = t0;
            out[(size_t)(wave * 2 + 1) * D_COUNT + (k0 + d)] = t1;
        }

        if (d < DOCS - 1) {
            cwriteP0(smem[0]);             // waits vmcnt on P0(2d+2)
            issueP1(2 * d + 2);
            cwriteP1(smem[0]);
            issueP0(2 * d + 3);
            sync();
        }
    }
}

extern "C" void kernel_launch(void* const* d_in, const int* in_sizes, int n_in,
                              void* d_out, int out_size, void* d_ws, size_t ws_size,
                              hipStream_t stream) {
    const float* Q = (const float*)d_in[0];
    const float* D = (const float*)d_in[1];
    float* out = (float*)d_out;
    maxsim_kernel<<<dim3(NBLK), dim3(512), 0, stream>>>(Q, D, out);
}